// Round 20
// baseline (1815.050 us; speedup 1.0000x reference)
//
#include <hip/hip_runtime.h>

#define TT 2048
#define BB 256
#define FF 64
#define HH 128
#define NT 512            // 8 waves; wave w owns units [16w, 16w+16)
#define MR 4              // batch rows per block (replicated to MFMA M=16)
#define NBLK (BB / MR)    // 64 blocks
#define HSTR 320          // h LDS row stride (bytes)

typedef _Float16 half8 __attribute__((ext_vector_type(8)));
typedef __fp16   fp16x2 __attribute__((ext_vector_type(2)));
typedef float    f32x4 __attribute__((ext_vector_type(4)));

#if __has_builtin(__builtin_amdgcn_rcpf)
#define FRCP(v) __builtin_amdgcn_rcpf(v)
#else
#define FRCP(v) (1.0f / (v))
#endif

// D = A(16x32 f16) * B(32x16 f16) + C(f32). Conventions verified r14-r16.
__device__ __forceinline__ f32x4 mf(f32x4 a, f32x4 b, f32x4 c) {
  return __builtin_amdgcn_mfma_f32_16x16x32_f16(
      __builtin_bit_cast(half8, a), __builtin_bit_cast(half8, b), c, 0, 0, 0);
}

// 8 f32 -> half8 (as f32x4 bit pattern) via packed RTZ converts (4 insts)
__device__ __forceinline__ f32x4 cvt8(const float4 a, const float4 b) {
  union { fp16x2 h[4]; f32x4 v; } u;
  u.h[0] = __builtin_amdgcn_cvt_pkrtz(a.x, a.y);
  u.h[1] = __builtin_amdgcn_cvt_pkrtz(a.z, a.w);
  u.h[2] = __builtin_amdgcn_cvt_pkrtz(b.x, b.y);
  u.h[3] = __builtin_amdgcn_cvt_pkrtz(b.z, b.w);
  return u.v;
}

// Hot-loop barrier without the vmcnt(0) drain (r9: proven equivalent).
__device__ __forceinline__ void step_barrier() {
  asm volatile("s_waitcnt lgkmcnt(0)" ::: "memory");
  __builtin_amdgcn_s_barrier();
  __builtin_amdgcn_sched_barrier(0);
}

__global__ void __launch_bounds__(NT)
__attribute__((amdgpu_waves_per_eu(2, 2)))
gru_scan_kernel(const float* __restrict__ x,     // [T,B,F]
                const float* __restrict__ Wi,    // [F,3H] r|z|n
                const float* __restrict__ bi,    // [3H]
                const float* __restrict__ Whrz,  // [H,2H] r|z
                const float* __restrict__ Whn,   // [H,H]
                const float* __restrict__ bn,    // [H]
                float* __restrict__ out)         // [T,B,H]
{
  const int tid   = threadIdx.x;
  const int w     = tid >> 6;     // wave 0..7
  const int l     = tid & 63;
  const int n16   = l & 15;       // C col within tile / A row m
  const int q     = l >> 4;       // k-chunk group; also this lane's batch row
  const int u     = 16 * w + n16; // hidden unit (this thread's column)
  const int rr    = n16 & 3;      // replicated A row -> batch row for A reads
  const int brow0 = blockIdx.x * MR;

  // h staging only (x lives in registers, fetched from global/L1)
  __shared__ __align__(16) char h_lds[2][MR * HSTR];   // 2 x 1280 B

  // ---- B-fragments (natural k order, col u) ----
  f32x4 Bhr[4], Bhz[4], Bhn2[4];
  f32x4 Bxr[2], Bxz[2], Bxn2[2];
  #pragma unroll
  for (int kt = 0; kt < 4; ++kt) {
    half8 fr, fz, fn;
    #pragma unroll
    for (int j = 0; j < 8; ++j) {
      const int k = 32 * kt + 8 * q + j;       // 0..127
      fr[j] = (_Float16)Whrz[(size_t)k * 256 + u];
      fz[j] = (_Float16)Whrz[(size_t)k * 256 + 128 + u];
      fn[j] = (_Float16)Whn[(size_t)k * 128 + u];
    }
    Bhr[kt]  = __builtin_bit_cast(f32x4, fr);
    Bhz[kt]  = __builtin_bit_cast(f32x4, fz);
    Bhn2[kt] = __builtin_bit_cast(f32x4, fn);
  }
  #pragma unroll
  for (int kt = 0; kt < 2; ++kt) {
    half8 fr, fz, fn;
    #pragma unroll
    for (int j = 0; j < 8; ++j) {
      const int k = 32 * kt + 8 * q + j;       // 0..63
      fr[j] = (_Float16)Wi[(size_t)k * 384 + u];
      fz[j] = (_Float16)Wi[(size_t)k * 384 + 128 + u];
      fn[j] = (_Float16)Wi[(size_t)k * 384 + 256 + u];
    }
    Bxr[kt]  = __builtin_bit_cast(f32x4, fr);
    Bxz[kt]  = __builtin_bit_cast(f32x4, fz);
    Bxn2[kt] = __builtin_bit_cast(f32x4, fn);
  }
  const float bR = bi[u], bZ = bi[128 + u], bX = bi[256 + u], bH = bn[u];
  const f32x4 biasR = f32x4{bR, bR, bR, bR};
  const f32x4 biasZ = f32x4{bZ, bZ, bZ, bZ};
  const f32x4 biasX = f32x4{bX, bX, bX, bX};
  const f32x4 biasH = f32x4{bH, bH, bH, bH};

  // h A-fragment byte offsets (row rr), and h'-write offset
  int hA[4];
  #pragma unroll
  for (int kt = 0; kt < 4; ++kt) hA[kt] = rr * HSTR + kt * 64 + q * 16;
  const int hW = q * HSTR + 2 * u;

  // x global addressing: this lane's frag kt = floats [kt*32+q*8, +8) of
  // row brow0+rr. Two float4 loads per frag.
  const size_t xrow0 = ((size_t)brow0 + rr) * FF + q * 8;

  // ---- init: h[0]=0; raw x loads for t=0 (slot A) and t=1 (slot B) ----
  if (tid < 64) {
    *(f32x4*)(h_lds[0] + (tid >> 4) * HSTR + (tid & 15) * 16) =
        f32x4{0.f, 0.f, 0.f, 0.f};
  }
  float4 rA0a, rA0b, rA1a, rA1b;   // even-step raw x (frag0: a,b; frag1: a,b)
  float4 rB0a, rB0b, rB1a, rB1b;   // odd-step raw x
  {
    const float* p0 = x + xrow0;                      // t=0
    rA0a = *(const float4*)(p0);
    rA0b = *(const float4*)(p0 + 4);
    rA1a = *(const float4*)(p0 + 32);
    rA1b = *(const float4*)(p0 + 36);
    const float* p1 = x + (size_t)BB * FF + xrow0;    // t=1
    rB0a = *(const float4*)(p1);
    rB0b = *(const float4*)(p1 + 4);
    rB1a = *(const float4*)(p1 + 32);
    rB1b = *(const float4*)(p1 + 36);
  }

  float h_old = 0.0f;
  float* outp = out + ((size_t)brow0 + q) * HH + u;
  __syncthreads();

  // one lane-local element from the replicated C fragment (row q)
#define SEL(C_) ((q < 2) ? ((q == 0) ? (C_)[0] : (C_)[1])                   \
                         : ((q == 2) ? (C_)[2] : (C_)[3]))

#define STEP(P, R0a, R0b, R1a, R1b)                                         \
  {                                                                         \
    const int t_ = tbase + (P);                                             \
    const char* hb = h_lds[(P) & 1];                                        \
    char* hdst = (char*)h_lds[((P) + 1) & 1];                               \
    /* 1) h reads first: latency drains under converts + x-MFMAs */         \
    f32x4 Ah0 = *(const f32x4*)(hb + hA[0]);                                \
    f32x4 Ah1 = *(const f32x4*)(hb + hA[1]);                                \
    f32x4 Ah2 = *(const f32x4*)(hb + hA[2]);                                \
    f32x4 Ah3 = *(const f32x4*)(hb + hA[3]);                                \
    /* 2) convert this step's raw x (loaded 2 steps ago) */                 \
    f32x4 Ax0 = cvt8(R0a, R0b);                                             \
    f32x4 Ax1 = cvt8(R1a, R1b);                                             \
    /* 3) refill the slot with x[t+2] (clamped; no dependency) */           \
    {                                                                       \
      const int t2 = (t_ + 2 < TT) ? t_ + 2 : TT - 1;                       \
      const float* p = x + (size_t)t2 * BB * FF + xrow0;                    \
      R0a = *(const float4*)(p);                                            \
      R0b = *(const float4*)(p + 4);                                        \
      R1a = *(const float4*)(p + 32);                                       \
      R1b = *(const float4*)(p + 36);                                       \
    }                                                                       \
    /* 4) chains: x-MFMAs lead (operands in regs), h-MFMAs follow */        \
    f32x4 Cr = mf(Ax0, Bxr[0], biasR);                                      \
    Cr = mf(Ax1, Bxr[1], Cr);                                               \
    f32x4 Cz = mf(Ax0, Bxz[0], biasZ);                                      \
    Cz = mf(Ax1, Bxz[1], Cz);                                               \
    f32x4 Cxn = mf(Ax0, Bxn2[0], biasX);                                    \
    Cxn = mf(Ax1, Bxn2[1], Cxn);                                            \
    Cr = mf(Ah0, Bhr[0], Cr); Cr = mf(Ah1, Bhr[1], Cr);                     \
    Cr = mf(Ah2, Bhr[2], Cr); Cr = mf(Ah3, Bhr[3], Cr);                     \
    Cz = mf(Ah0, Bhz[0], Cz); Cz = mf(Ah1, Bhz[1], Cz);                     \
    Cz = mf(Ah2, Bhz[2], Cz); Cz = mf(Ah3, Bhz[3], Cz);                     \
    f32x4 Chn = mf(Ah0, Bhn2[0], biasH);                                    \
    Chn = mf(Ah1, Bhn2[1], Chn); Chn = mf(Ah2, Bhn2[2], Chn);               \
    Chn = mf(Ah3, Bhn2[3], Chn);                                            \
    /* 5) fused 5-trans gate on this lane's (row q, col n16) element */     \
    const float cr  = SEL(Cr);                                              \
    const float cz  = SEL(Cz);                                              \
    const float chn = SEL(Chn);                                             \
    const float cxn = SEL(Cxn);                                             \
    const float A_ = __expf(-cr);                                           \
    const float rg = FRCP(1.0f + A_);                                       \
    const float B_ = __expf(-cz);                                           \
    const float na = cxn + rg * chn;                                        \
    const float E_ = __expf(2.0f * na);                                     \
    const float Ep1 = E_ + 1.0f;                                            \
    const float num = h_old * Ep1 + B_ * (E_ - 1.0f);                       \
    const float hv  = num * FRCP(Ep1 * (1.0f + B_));                        \
    h_old = hv;                                                             \
    *(_Float16*)(hdst + hW) = (_Float16)hv;                                 \
    *outp = hv;                                                             \
    outp += (size_t)BB * HH;                                                \
    step_barrier();                                                         \
  }

  for (int tbase = 0; tbase < TT; tbase += 2) {
    STEP(0, rA0a, rA0b, rA1a, rA1b)
    STEP(1, rB0a, rB0b, rB1a, rB1b)
  }
#undef STEP
#undef SEL
}

extern "C" void kernel_launch(void* const* d_in, const int* in_sizes, int n_in,
                              void* d_out, int out_size, void* d_ws, size_t ws_size,
                              hipStream_t stream) {
  const float* x    = (const float*)d_in[0];
  const float* Wi   = (const float*)d_in[1];
  const float* bi   = (const float*)d_in[2];
  const float* Whrz = (const float*)d_in[3];
  const float* Whn  = (const float*)d_in[4];
  const float* bn   = (const float*)d_in[5];
  float* out = (float*)d_out;

  gru_scan_kernel<<<dim3(NBLK), dim3(NT), 0, stream>>>(
      x, Wi, bi, Whrz, Whn, bn, out);
}

// Round 21
// 894.430 us; speedup vs baseline: 2.0293x; 2.0293x over previous
//
#include <hip/hip_runtime.h>

#define TT 2048
#define BB 256
#define FF 64
#define HH 128
#define NT 512            // 8 waves; wave w owns units [16w, 16w+16)
#define MR 4              // valid batch rows per block
#define NBLK (BB / MR)    // 64 blocks
#define RS (BB * FF / 4)  // x row stride in float4
#define HSTR 320          // LDS row stride (bytes): rows r, r+2 share banks (2-way, free)

typedef _Float16 half8 __attribute__((ext_vector_type(8)));
typedef _Float16 half4 __attribute__((ext_vector_type(4)));
typedef float    f32x4 __attribute__((ext_vector_type(4)));

#if __has_builtin(__builtin_amdgcn_rcpf)
#define FRCP(v) __builtin_amdgcn_rcpf(v)
#else
#define FRCP(v) (1.0f / (v))
#endif

// D = A(16x32 f16) * B(32x16 f16) + C(f32). Same operand conventions as the
// round-14/15 kernels (both passed, absmax 0.0039).
__device__ __forceinline__ f32x4 mf(f32x4 a, f32x4 b, f32x4 c) {
  return __builtin_amdgcn_mfma_f32_16x16x32_f16(
      __builtin_bit_cast(half8, a), __builtin_bit_cast(half8, b), c, 0, 0, 0);
}

// Hot-loop barrier without the vmcnt(0) drain (r9: proven equivalent).
__device__ __forceinline__ void step_barrier() {
  asm volatile("s_waitcnt lgkmcnt(0)" ::: "memory");
  __builtin_amdgcn_s_barrier();
  __builtin_amdgcn_sched_barrier(0);
}

__global__ void __launch_bounds__(NT)
__attribute__((amdgpu_waves_per_eu(2, 2)))
gru_scan_kernel(const float* __restrict__ x,     // [T,B,F]
                const float* __restrict__ Wi,    // [F,3H] r|z|n
                const float* __restrict__ bi,    // [3H]
                const float* __restrict__ Whrz,  // [H,2H] r|z
                const float* __restrict__ Whn,   // [H,H]
                const float* __restrict__ bn,    // [H]
                float* __restrict__ out)         // [T,B,H]
{
  const int tid   = threadIdx.x;
  const int w     = tid >> 6;     // wave 0..7
  const int l     = tid & 63;
  const int n16   = l & 15;       // C col within tile / A row m
  const int q     = l >> 4;       // k-chunk group; also this lane's batch row
  const int u     = 16 * w + n16; // hidden unit (this thread's column)
  const int rr    = n16 & 3;      // replicated A row -> batch row for A reads
  const int brow0 = blockIdx.x * MR;

  // Compact 4-row staging, f16, row stride 320B (16B-aligned; rows r and r+2
  // bank-alias 2-way which is free). Data bytes [0,256) of each row.
  __shared__ __align__(16) char h_lds[2][MR * HSTR];   // 2 x 1280 B
  __shared__ __align__(16) char x_lds[4][MR * HSTR];   // 4 x 1280 B

  // ---- B-fragments (natural k order, col u). NO pins: MFMA reads AGPRs
  // natively; r15's "+v" pins forced AGPR<->VGPR churn. ----
  f32x4 Bhr[4], Bhz[4], Bhn2[4];
  f32x4 Bxr[2], Bxz[2], Bxn2[2];
  #pragma unroll
  for (int kt = 0; kt < 4; ++kt) {
    half8 fr, fz, fn;
    #pragma unroll
    for (int j = 0; j < 8; ++j) {
      const int k = 32 * kt + 8 * q + j;       // 0..127
      fr[j] = (_Float16)Whrz[(size_t)k * 256 + u];
      fz[j] = (_Float16)Whrz[(size_t)k * 256 + 128 + u];
      fn[j] = (_Float16)Whn[(size_t)k * 128 + u];
    }
    Bhr[kt]  = __builtin_bit_cast(f32x4, fr);
    Bhz[kt]  = __builtin_bit_cast(f32x4, fz);
    Bhn2[kt] = __builtin_bit_cast(f32x4, fn);
  }
  #pragma unroll
  for (int kt = 0; kt < 2; ++kt) {
    half8 fr, fz, fn;
    #pragma unroll
    for (int j = 0; j < 8; ++j) {
      const int k = 32 * kt + 8 * q + j;       // 0..63
      fr[j] = (_Float16)Wi[(size_t)k * 384 + u];
      fz[j] = (_Float16)Wi[(size_t)k * 384 + 128 + u];
      fn[j] = (_Float16)Wi[(size_t)k * 384 + 256 + u];
    }
    Bxr[kt]  = __builtin_bit_cast(f32x4, fr);
    Bxz[kt]  = __builtin_bit_cast(f32x4, fz);
    Bxn2[kt] = __builtin_bit_cast(f32x4, fn);
  }
  const float bR = bi[u], bZ = bi[128 + u], bX = bi[256 + u], bH = bn[u];
  const f32x4 biasR = f32x4{bR, bR, bR, bR};
  const f32x4 biasZ = f32x4{bZ, bZ, bZ, bZ};
  const f32x4 biasX = f32x4{bX, bX, bX, bX};
  const f32x4 biasH = f32x4{bH, bH, bH, bH};

  // A-fragment byte offsets: row rr, k-chunk (kt, q); byte = rr*HSTR + 2*k.
  int hA[4], xA[2];
  #pragma unroll
  for (int kt = 0; kt < 4; ++kt) hA[kt] = rr * HSTR + kt * 64 + q * 16;
  #pragma unroll
  for (int kt = 0; kt < 2; ++kt) xA[kt] = rr * HSTR + kt * 64 + q * 16;

  // h'-write: this lane's (batch row q, unit u)
  const int hW = q * HSTR + 2 * u;

  // x staging: 64 loader threads -> (row, 4-feature group)
  const bool loader = (tid < 64);
  const int  srow   = tid >> 4;   // 0..3 (loader only)
  const int  sc     = tid & 15;
  const int  sbyte  = srow * HSTR + sc * 8;

  // ---- init: h[0] buffer = 0; stage x[0],x[1]; prefetch x[2],x[3] ----
  if (loader) {
    *(f32x4*)(h_lds[0] + srow * HSTR + sc * 16) = f32x4{0.f, 0.f, 0.f, 0.f};
    #pragma unroll
    for (int s = 0; s < 2; ++s) {
      const float4 v =
          *(const float4*)(x + ((size_t)s * BB + brow0 + srow) * FF + sc * 4);
      half4 hf;
      hf[0] = (_Float16)v.x; hf[1] = (_Float16)v.y;
      hf[2] = (_Float16)v.z; hf[3] = (_Float16)v.w;
      *(half4*)(x_lds[s] + sbyte) = hf;
    }
  }
  const float4* xsrc =
      (const float4*)(x + ((size_t)2 * BB + brow0 + srow) * FF + sc * 4);
  float4 xva, xvb;
  if (loader) {
    xva = xsrc[0];              // x[2]
    xvb = xsrc[(size_t)RS];     // x[3]
    xsrc += 2 * (size_t)RS;     // -> x[4]
  }

  float h_old = 0.0f;           // this lane's (row q, unit u), fp32
  float* outp = out + ((size_t)brow0 + q) * HH + u;
  __syncthreads();

#define STEP(P, XV)                                                         \
  {                                                                         \
    const int t_ = tbase + (P);                                             \
    const char* hb = h_lds[(P) & 1];                                        \
    const char* xb = x_lds[(P) & 3];                                        \
    f32x4 Ah0 = *(const f32x4*)(hb + hA[0]);                                \
    f32x4 Ah1 = *(const f32x4*)(hb + hA[1]);                                \
    f32x4 Ah2 = *(const f32x4*)(hb + hA[2]);                                \
    f32x4 Ah3 = *(const f32x4*)(hb + hA[3]);                                \
    f32x4 Ax0 = *(const f32x4*)(xb + xA[0]);                                \
    f32x4 Ax1 = *(const f32x4*)(xb + xA[1]);                                \
    if (loader) {                                                           \
      if (t_ + 2 < TT) {                                                    \
        half4 hf;                                                           \
        hf[0] = (_Float16)XV.x; hf[1] = (_Float16)XV.y;                     \
        hf[2] = (_Float16)XV.z; hf[3] = (_Float16)XV.w;                     \
        *(half4*)(x_lds[((P) + 2) & 3] + sbyte) = hf;        /* x[t+2] */   \
      }                                                                     \
      if (t_ + 4 < TT) { XV = *xsrc; xsrc += RS; }           /* x[t+4] */   \
    }                                                                       \
    f32x4 Cr = mf(Ah0, Bhr[0], biasR);                                      \
    Cr = mf(Ah1, Bhr[1], Cr); Cr = mf(Ah2, Bhr[2], Cr);                     \
    Cr = mf(Ah3, Bhr[3], Cr);                                               \
    Cr = mf(Ax0, Bxr[0], Cr); Cr = mf(Ax1, Bxr[1], Cr);                     \
    f32x4 Cz = mf(Ah0, Bhz[0], biasZ);                                      \
    Cz = mf(Ah1, Bhz[1], Cz); Cz = mf(Ah2, Bhz[2], Cz);                     \
    Cz = mf(Ah3, Bhz[3], Cz);                                               \
    Cz = mf(Ax0, Bxz[0], Cz); Cz = mf(Ax1, Bxz[1], Cz);                     \
    f32x4 Chn = mf(Ah0, Bhn2[0], biasH);                                    \
    Chn = mf(Ah1, Bhn2[1], Chn); Chn = mf(Ah2, Bhn2[2], Chn);               \
    Chn = mf(Ah3, Bhn2[3], Chn);                                            \
    f32x4 Cxn = mf(Ax0, Bxn2[0], biasX);                                    \
    Cxn = mf(Ax1, Bxn2[1], Cxn);                                            \
    /* replicated rows: C reg i == batch row i in EVERY lane; this lane    */\
    /* gates (row q, col n16) via constant-index selects (no shuffles).    */\
    const float cr  = (q < 2) ? ((q == 0) ? Cr[0]  : Cr[1])                 \
                              : ((q == 2) ? Cr[2]  : Cr[3]);                \
    const float cz  = (q < 2) ? ((q == 0) ? Cz[0]  : Cz[1])                 \
                              : ((q == 2) ? Cz[2]  : Cz[3]);                \
    const float chn = (q < 2) ? ((q == 0) ? Chn[0] : Chn[1])                \
                              : ((q == 2) ? Chn[2] : Chn[3]);               \
    const float cxn = (q < 2) ? ((q == 0) ? Cxn[0] : Cxn[1])                \
                              : ((q == 2) ? Cxn[2] : Cxn[3]);               \
    const float A_ = __expf(-cr);                                           \
    const float rg = FRCP(1.0f + A_);                                       \
    const float B_ = __expf(-cz);                                           \
    const float na = cxn + rg * chn;                                        \
    const float E_ = __expf(2.0f * na);                                     \
    const float Ep1 = E_ + 1.0f;                                            \
    const float num = h_old * Ep1 + B_ * (E_ - 1.0f);                       \
    const float hv  = num * FRCP(Ep1 * (1.0f + B_));                        \
    h_old = hv;                                                             \
    *(_Float16*)(h_lds[((P) + 1) & 1] + hW) = (_Float16)hv;                 \
    *outp = hv;                                                             \
    outp += (size_t)BB * HH;                                                \
    step_barrier();                                                         \
  }

  for (int tbase = 0; tbase < TT; tbase += 4) {
    STEP(0, xva)
    STEP(1, xvb)
    STEP(2, xva)
    STEP(3, xvb)
  }
#undef STEP
}

extern "C" void kernel_launch(void* const* d_in, const int* in_sizes, int n_in,
                              void* d_out, int out_size, void* d_ws, size_t ws_size,
                              hipStream_t stream) {
  const float* x    = (const float*)d_in[0];
  const float* Wi   = (const float*)d_in[1];
  const float* bi   = (const float*)d_in[2];
  const float* Whrz = (const float*)d_in[3];
  const float* Whn  = (const float*)d_in[4];
  const float* bn   = (const float*)d_in[5];
  float* out = (float*)d_out;

  gru_scan_kernel<<<dim3(NBLK), dim3(NT), 0, stream>>>(
      x, Wi, bi, Whrz, Whn, bn, out);
}

// Round 23
// 878.925 us; speedup vs baseline: 2.0651x; 1.0176x over previous
//
#include <hip/hip_runtime.h>

#define TT 2048
#define BB 256
#define FF 64
#define HH 128
#define NT 512            // 8 waves; wave w owns units [16w, 16w+16)
#define MR 4              // valid batch rows per block
#define NBLK (BB / MR)    // 64 blocks
#define RS (BB * FF / 4)  // x row stride in float4
#define HSTR 320          // LDS row stride (bytes): rows r, r+2 share banks (2-way, free)

#define LOG2E 1.44269504088896340736f

typedef _Float16 half8 __attribute__((ext_vector_type(8)));
typedef _Float16 half4 __attribute__((ext_vector_type(4)));
typedef float    f32x4 __attribute__((ext_vector_type(4)));

#if __has_builtin(__builtin_amdgcn_rcpf)
#define FRCP(v) __builtin_amdgcn_rcpf(v)
#else
#define FRCP(v) (1.0f / (v))
#endif

#if __has_builtin(__builtin_amdgcn_exp2f)
#define FEXP2(v) __builtin_amdgcn_exp2f(v)
#else
#define FEXP2(v) exp2f(v)
#endif

// D = A(16x32 f16) * B(32x16 f16) + C(f32). Operand conventions verified
// r14-r16/r21 (absmax 0.0039 each).
__device__ __forceinline__ f32x4 mf(f32x4 a, f32x4 b, f32x4 c) {
  return __builtin_amdgcn_mfma_f32_16x16x32_f16(
      __builtin_bit_cast(half8, a), __builtin_bit_cast(half8, b), c, 0, 0, 0);
}

// Hot-loop barrier without the vmcnt(0) drain (r9: proven equivalent).
__device__ __forceinline__ void step_barrier() {
  asm volatile("s_waitcnt lgkmcnt(0)" ::: "memory");
  __builtin_amdgcn_s_barrier();
  __builtin_amdgcn_sched_barrier(0);
}

__global__ void __launch_bounds__(NT)
__attribute__((amdgpu_waves_per_eu(2, 2)))
gru_scan_kernel(const float* __restrict__ x,     // [T,B,F]
                const float* __restrict__ Wi,    // [F,3H] r|z|n
                const float* __restrict__ bi,    // [3H]
                const float* __restrict__ Whrz,  // [H,2H] r|z
                const float* __restrict__ Whn,   // [H,H]
                const float* __restrict__ bn,    // [H]
                float* __restrict__ out)         // [T,B,H]
{
  const int tid   = threadIdx.x;
  const int w     = tid >> 6;     // wave 0..7
  const int l     = tid & 63;
  const int n16   = l & 15;       // C col within tile / A row m
  const int q     = l >> 4;       // k-chunk group; also this lane's batch row
  const int u     = 16 * w + n16; // hidden unit (this thread's column)
  const int rr    = n16 & 3;      // replicated A row -> batch row for A reads
  const int brow0 = blockIdx.x * MR;

  // Compact 4-row staging, f16, row stride 320B.
  __shared__ __align__(16) char h_lds[2][MR * HSTR];   // 2 x 1280 B
  __shared__ __align__(16) char x_lds[4][MR * HSTR];   // 4 x 1280 B

  // ---- B-fragments, with exp2 pre-scaling folded into the weights:
  //  r,z gates: scale by -LOG2E (absorbs the gate's negate AND the
  //  expf->exp2 conversion mul);  n gates: scale by +2*LOG2E (absorbs
  //  tanh's 2x and the conversion mul). Gate tail then uses raw exp2.
  const float SRZ = -LOG2E;
  const float SN  = 2.0f * LOG2E;
  f32x4 Bhr[4], Bhz[4], Bhn2[4];
  f32x4 Bxr[2], Bxz[2], Bxn2[2];
  #pragma unroll
  for (int kt = 0; kt < 4; ++kt) {
    half8 fr, fz, fn;
    #pragma unroll
    for (int j = 0; j < 8; ++j) {
      const int k = 32 * kt + 8 * q + j;       // 0..127
      fr[j] = (_Float16)(SRZ * Whrz[(size_t)k * 256 + u]);
      fz[j] = (_Float16)(SRZ * Whrz[(size_t)k * 256 + 128 + u]);
      fn[j] = (_Float16)(SN * Whn[(size_t)k * 128 + u]);
    }
    Bhr[kt]  = __builtin_bit_cast(f32x4, fr);
    Bhz[kt]  = __builtin_bit_cast(f32x4, fz);
    Bhn2[kt] = __builtin_bit_cast(f32x4, fn);
  }
  #pragma unroll
  for (int kt = 0; kt < 2; ++kt) {
    half8 fr, fz, fn;
    #pragma unroll
    for (int j = 0; j < 8; ++j) {
      const int k = 32 * kt + 8 * q + j;       // 0..63
      fr[j] = (_Float16)(SRZ * Wi[(size_t)k * 384 + u]);
      fz[j] = (_Float16)(SRZ * Wi[(size_t)k * 384 + 128 + u]);
      fn[j] = (_Float16)(SN * Wi[(size_t)k * 384 + 256 + u]);
    }
    Bxr[kt]  = __builtin_bit_cast(f32x4, fr);
    Bxz[kt]  = __builtin_bit_cast(f32x4, fz);
    Bxn2[kt] = __builtin_bit_cast(f32x4, fn);
  }
  const float bR = SRZ * bi[u];
  const float bZ = SRZ * bi[128 + u];
  const float bX = SN * bi[256 + u];
  const float bH = SN * bn[u];
  const f32x4 biasR = f32x4{bR, bR, bR, bR};
  const f32x4 biasZ = f32x4{bZ, bZ, bZ, bZ};
  const f32x4 biasX = f32x4{bX, bX, bX, bX};
  const f32x4 biasH = f32x4{bH, bH, bH, bH};

  // A-fragment byte offsets: row rr, k-chunk (kt, q); byte = rr*HSTR + 2*k.
  int hA[4], xA[2];
  #pragma unroll
  for (int kt = 0; kt < 4; ++kt) hA[kt] = rr * HSTR + kt * 64 + q * 16;
  #pragma unroll
  for (int kt = 0; kt < 2; ++kt) xA[kt] = rr * HSTR + kt * 64 + q * 16;

  // h'-write: this lane's (batch row q, unit u)
  const int hW = q * HSTR + 2 * u;

  // x staging: 64 loader threads -> (row, 4-feature group)
  const bool loader = (tid < 64);
  const int  srow   = tid >> 4;   // 0..3 (loader only)
  const int  sc     = tid & 15;
  const int  sbyte  = srow * HSTR + sc * 8;

  // ---- init: h[0] buffer = 0; stage x[0],x[1]; prefetch x[2],x[3] ----
  if (loader) {
    *(f32x4*)(h_lds[0] + srow * HSTR + sc * 16) = f32x4{0.f, 0.f, 0.f, 0.f};
    #pragma unroll
    for (int s = 0; s < 2; ++s) {
      const float4 v =
          *(const float4*)(x + ((size_t)s * BB + brow0 + srow) * FF + sc * 4);
      half4 hf;
      hf[0] = (_Float16)v.x; hf[1] = (_Float16)v.y;
      hf[2] = (_Float16)v.z; hf[3] = (_Float16)v.w;
      *(half4*)(x_lds[s] + sbyte) = hf;
    }
  }
  const float4* xsrc =
      (const float4*)(x + ((size_t)2 * BB + brow0 + srow) * FF + sc * 4);
  float4 xva, xvb;
  if (loader) {
    xva = xsrc[0];              // x[2]
    xvb = xsrc[(size_t)RS];     // x[3]
    xsrc += 2 * (size_t)RS;     // -> x[4]
  }

  float h_old = 0.0f;           // this lane's (row q, unit u), fp32
  float* outp = out + ((size_t)brow0 + q) * HH + u;
  __syncthreads();

#define STEP(P, XV)                                                         \
  {                                                                         \
    const int t_ = tbase + (P);                                             \
    const char* hb = h_lds[(P) & 1];                                        \
    const char* xb = x_lds[(P) & 3];                                        \
    f32x4 Ah0 = *(const f32x4*)(hb + hA[0]);                                \
    f32x4 Ah1 = *(const f32x4*)(hb + hA[1]);                                \
    f32x4 Ah2 = *(const f32x4*)(hb + hA[2]);                                \
    f32x4 Ah3 = *(const f32x4*)(hb + hA[3]);                                \
    f32x4 Ax0 = *(const f32x4*)(xb + xA[0]);                                \
    f32x4 Ax1 = *(const f32x4*)(xb + xA[1]);                                \
    if (loader) {                                                           \
      if (t_ + 2 < TT) {                                                    \
        half4 hf;                                                           \
        hf[0] = (_Float16)XV.x; hf[1] = (_Float16)XV.y;                     \
        hf[2] = (_Float16)XV.z; hf[3] = (_Float16)XV.w;                     \
        *(half4*)(x_lds[((P) + 2) & 3] + sbyte) = hf;        /* x[t+2] */   \
      }                                                                     \
      if (t_ + 4 < TT) { XV = *xsrc; xsrc += RS; }           /* x[t+4] */   \
    }                                                                       \
    f32x4 Cr = mf(Ah0, Bhr[0], biasR);                                      \
    Cr = mf(Ah1, Bhr[1], Cr); Cr = mf(Ah2, Bhr[2], Cr);                     \
    Cr = mf(Ah3, Bhr[3], Cr);                                               \
    Cr = mf(Ax0, Bxr[0], Cr); Cr = mf(Ax1, Bxr[1], Cr);                     \
    f32x4 Cz = mf(Ah0, Bhz[0], biasZ);                                      \
    Cz = mf(Ah1, Bhz[1], Cz); Cz = mf(Ah2, Bhz[2], Cz);                     \
    Cz = mf(Ah3, Bhz[3], Cz);                                               \
    Cz = mf(Ax0, Bxz[0], Cz); Cz = mf(Ax1, Bxz[1], Cz);                     \
    f32x4 Chn = mf(Ah0, Bhn2[0], biasH);                                    \
    Chn = mf(Ah1, Bhn2[1], Chn); Chn = mf(Ah2, Bhn2[2], Chn);               \
    Chn = mf(Ah3, Bhn2[3], Chn);                                            \
    f32x4 Cxn = mf(Ax0, Bxn2[0], biasX);                                    \
    Cxn = mf(Ax1, Bxn2[1], Cxn);                                            \
    /* replicated rows: C reg i == batch row i in EVERY lane */             \
    const float cr  = (q < 2) ? ((q == 0) ? Cr[0]  : Cr[1])                 \
                              : ((q == 2) ? Cr[2]  : Cr[3]);                \
    const float cz  = (q < 2) ? ((q == 0) ? Cz[0]  : Cz[1])                 \
                              : ((q == 2) ? Cz[2]  : Cz[3]);                \
    const float chn = (q < 2) ? ((q == 0) ? Chn[0] : Chn[1])                \
                              : ((q == 2) ? Chn[2] : Chn[3]);               \
    const float cxn = (q < 2) ? ((q == 0) ? Cxn[0] : Cxn[1])                \
                              : ((q == 2) ? Cxn[2] : Cxn[3]);               \
    /* gate tail: weights pre-scaled -> raw v_exp_f32, no muls on chain.   */\
    /* cr = -log2e*pr: A_ = 2^cr = e^-pr.  cz likewise.                    */\
    /* cxn,chn scaled by 2log2e: E_ = 2^(cxn + rg*chn) = e^(2*na).         */\
    const float A_ = FEXP2(cr);                                             \
    const float rg = FRCP(1.0f + A_);                                       \
    const float B_ = FEXP2(cz);                                             \
    const float E_ = FEXP2(cxn + rg * chn);                                 \
    const float Ep1 = E_ + 1.0f;                                            \
    const float num = h_old * Ep1 + B_ * (E_ - 1.0f);                       \
    const float hv  = num * FRCP(Ep1 * (1.0f + B_));                        \
    h_old = hv;                                                             \
    *(_Float16*)(h_lds[((P) + 1) & 1] + hW) = (_Float16)hv;                 \
    *outp = hv;                                                             \
    outp += (size_t)BB * HH;                                                \
    step_barrier();                                                         \
  }

  for (int tbase = 0; tbase < TT; tbase += 4) {
    STEP(0, xva)
    STEP(1, xvb)
    STEP(2, xva)
    STEP(3, xvb)
  }
#undef STEP
}

extern "C" void kernel_launch(void* const* d_in, const int* in_sizes, int n_in,
                              void* d_out, int out_size, void* d_ws, size_t ws_size,
                              hipStream_t stream) {
  const float* x    = (const float*)d_in[0];
  const float* Wi   = (const float*)d_in[1];
  const float* bi   = (const float*)d_in[2];
  const float* Whrz = (const float*)d_in[3];
  const float* Whn  = (const float*)d_in[4];
  const float* bn   = (const float*)d_in[5];
  float* out = (float*)d_out;

  gru_scan_kernel<<<dim3(NBLK), dim3(NT), 0, stream>>>(
      x, Wi, bi, Whrz, Whn, bn, out);
}